// Round 6
// baseline (614.851 us; speedup 1.0000x reference)
//
#include <hip/hip_runtime.h>
#include <hip/hip_bf16.h>

// BitNet 4-layer MLP forward, MI355X — round 6: gemm2p = 256^2, BK=128 i8,
// double-buffered, MINIMAL sync (2 barriers + 1 counted vmcnt per K-tile).
// Round 3-5 showed the 8-phase graft is sync-overhead-bound at 1 block/CU
// (8 barriers/K-tile ~ 5200 cy overhead vs 2611 cy MFMA). Amortize instead.

typedef __attribute__((ext_vector_type(4))) int i32x4_t;

#define GLDS16(g, l) __builtin_amdgcn_global_load_lds( \
    (const __attribute__((address_space(1))) unsigned int*)(g), \
    (__attribute__((address_space(3))) unsigned int*)(l), 16, 0, 0)

static __device__ __forceinline__ unsigned char f2i8(float f) {
  return (unsigned char)(int)f;   // f already rint'ed and clipped
}

// ---------------- weight abs-mean (deterministic two-stage fp64) ------------
__global__ __launch_bounds__(256) void absmean_part_k(
    const float* __restrict__ W, int n4, double* __restrict__ part)
{
  double s = 0.0;
  const int stride = gridDim.x * 256;
  for (int i = blockIdx.x * 256 + threadIdx.x; i < n4; i += stride) {
    float4 v = ((const float4*)W)[i];
    s += (double)fabsf(v.x); s += (double)fabsf(v.y);
    s += (double)fabsf(v.z); s += (double)fabsf(v.w);
  }
  __shared__ double sd[256];
  sd[threadIdx.x] = s;
  __syncthreads();
  for (int st = 128; st > 0; st >>= 1) {
    if (threadIdx.x < st) sd[threadIdx.x] += sd[threadIdx.x + st];
    __syncthreads();
  }
  if (threadIdx.x == 0) part[blockIdx.x] = sd[0];
}

__global__ __launch_bounds__(256) void absmean_fin_k(
    const double* __restrict__ part, int nPart, double n,
    float* __restrict__ wsc, int widx)
{
  __shared__ double sd[256];
  double s = 0.0;
  for (int i = threadIdx.x; i < nPart; i += 256) s += part[i];
  sd[threadIdx.x] = s;
  __syncthreads();
  for (int st = 128; st > 0; st >>= 1) {
    if (threadIdx.x < st) sd[threadIdx.x] += sd[threadIdx.x + st];
    __syncthreads();
  }
  if (threadIdx.x == 0) {
    float mean = (float)(sd[0] / n);
    float scale = 1.f / fmaxf(mean, 1e-5f);
    wsc[widx * 2]     = scale;
    wsc[widx * 2 + 1] = 1.f / scale;
  }
}

// ---------------- weight ternary quantization to i8 {-1,0,1} ----------------
__global__ __launch_bounds__(256) void quant_w_k(
    const float* __restrict__ W, unsigned int* __restrict__ Wq,
    const float* __restrict__ wsc, int widx, int n4)
{
  const float s = wsc[widx * 2];
  const int stride = gridDim.x * 256;
  for (int i = blockIdx.x * 256 + threadIdx.x; i < n4; i += stride) {
    float4 v = ((const float4*)W)[i];
    unsigned int u =
        (unsigned int)f2i8(fminf(fmaxf(rintf(v.x * s), -1.f), 1.f)) |
        ((unsigned int)f2i8(fminf(fmaxf(rintf(v.y * s), -1.f), 1.f)) << 8) |
        ((unsigned int)f2i8(fminf(fmaxf(rintf(v.z * s), -1.f), 1.f)) << 16) |
        ((unsigned int)f2i8(fminf(fmaxf(rintf(v.w * s), -1.f), 1.f)) << 24);
    Wq[i] = u;
  }
}

// ---------------- per-row activation quantization to i8 ---------------------
template<int D>
__global__ __launch_bounds__(256) void act_quant_k(
    const float* __restrict__ X, unsigned int* __restrict__ Xq,
    float* __restrict__ inv_sa)
{
  constexpr int PER = D / 1024;
  const int row = blockIdx.x, tid = threadIdx.x;
  const float4* xr = (const float4*)(X + (size_t)row * D);
  float4 v[PER];
  float m = 0.f;
  #pragma unroll
  for (int i = 0; i < PER; ++i) {
    v[i] = xr[tid + 256 * i];
    m = fmaxf(m, fmaxf(fmaxf(fabsf(v[i].x), fabsf(v[i].y)),
                       fmaxf(fabsf(v[i].z), fabsf(v[i].w))));
  }
  #pragma unroll
  for (int off = 32; off >= 1; off >>= 1) m = fmaxf(m, __shfl_xor(m, off));
  __shared__ float wm[4];
  if ((tid & 63) == 0) wm[tid >> 6] = m;
  __syncthreads();
  m = fmaxf(fmaxf(wm[0], wm[1]), fmaxf(wm[2], wm[3]));
  const float s = 127.f / fmaxf(m, 1e-5f);
  if (tid == 0) inv_sa[row] = 1.f / s;
  unsigned int* oq = Xq + (size_t)row * (D / 4);
  #pragma unroll
  for (int i = 0; i < PER; ++i) {
    unsigned int u =
        (unsigned int)f2i8(fminf(fmaxf(rintf(v[i].x * s), -128.f), 127.f)) |
        ((unsigned int)f2i8(fminf(fmaxf(rintf(v[i].y * s), -128.f), 127.f)) << 8) |
        ((unsigned int)f2i8(fminf(fmaxf(rintf(v[i].z * s), -128.f), 127.f)) << 16) |
        ((unsigned int)f2i8(fminf(fmaxf(rintf(v[i].w * s), -128.f), 127.f)) << 24);
    oq[tid + 256 * i] = u;
  }
}

// ---------------- 128^2 2-phase i8 GEMM (proven; used for L1/L4) ------------
template<int K, int N, bool TANH>
__global__ __launch_bounds__(256) void gemm_bt(
    const signed char* __restrict__ A, const signed char* __restrict__ W,
    const float* __restrict__ inv_sa, const float* __restrict__ wsc, int widx,
    const float* __restrict__ bias, float* __restrict__ out)
{
  __shared__ __align__(16) signed char As[128 * 64];
  __shared__ __align__(16) signed char Bs[128 * 64];
  const int tid = threadIdx.x;
  const int wv = tid >> 6, ln = tid & 63;
  const int bm = blockIdx.y, bn = blockIdx.x;
  const int wr = wv >> 1, wc = wv & 1;
  const signed char* Ab = A + (size_t)bm * 128 * K;
  const signed char* Wb = W + (size_t)bn * 128 * K;
  i32x4_t acc[4][4];
  #pragma unroll
  for (int m = 0; m < 4; ++m)
    #pragma unroll
    for (int n = 0; n < 4; ++n) acc[m][n] = (i32x4_t){0, 0, 0, 0};

  for (int k0 = 0; k0 < K; k0 += 64) {
    #pragma unroll
    for (int l = 0; l < 2; ++l) {
      const int c = l * 256 + wv * 64 + ln;
      const int row = c >> 2;
      const int kc = (c & 3) * 16;
      GLDS16(Ab + (size_t)row * K + k0 + kc, As + (l * 256 + wv * 64) * 16);
      GLDS16(Wb + (size_t)row * K + k0 + kc, Bs + (l * 256 + wv * 64) * 16);
    }
    __syncthreads();
    i32x4_t aw[4], bw[4];
    #pragma unroll
    for (int m = 0; m < 4; ++m)
      aw[m] = *(const i32x4_t*)(As + (wr * 64 + m * 16 + (ln & 15)) * 64 + (ln >> 4) * 16);
    #pragma unroll
    for (int n = 0; n < 4; ++n)
      bw[n] = *(const i32x4_t*)(Bs + (wc * 64 + n * 16 + (ln & 15)) * 64 + (ln >> 4) * 16);
    #pragma unroll
    for (int m = 0; m < 4; ++m)
      #pragma unroll
      for (int n = 0; n < 4; ++n)
        acc[m][n] = __builtin_amdgcn_mfma_i32_16x16x64_i8(aw[m], bw[n], acc[m][n], 0, 0, 0);
    __syncthreads();
  }

  const float invw = wsc[widx * 2 + 1];
  #pragma unroll
  for (int m = 0; m < 4; ++m) {
    const int gb0 = bm * 128 + wr * 64 + m * 16 + ((ln >> 4) << 2);
    #pragma unroll
    for (int r = 0; r < 4; ++r) {
      const int gb = gb0 + r;
      const float fa = inv_sa[gb] * invw;
      #pragma unroll
      for (int n = 0; n < 4; ++n) {
        const int go = bn * 128 + wc * 64 + n * 16 + (ln & 15);
        const float v = (float)acc[m][n][r] * fa + bias[go];
        out[(size_t)gb * N + go] = TANH ? tanhf(v) : v;
      }
    }
  }
}

// ---------------- 256^2 dbuf i8 GEMM, minimal sync (used for L2/L3) ---------
// BM=BN=256, BK=128 i8. 8 waves (2M x 4N), per-wave output 128x64.
// LDS 128KB: buf{0,1} x { A 32KB, B 32KB }. 3-bit XOR swizzle (round 4,
// conflict-free verified). Per K-tile: reads+MFMA (compiler-interleaved
// lgkm waits) -> lgkm(0)+barrier -> stage(t+2)->buf[cur] -> vmcnt(8)
// (tile t+1 confirmed; t+2 stays in flight) -> barrier. 2 barriers/tile.
template<int K, int N, bool TANH>
__global__ __launch_bounds__(512, 2) void gemm2p(
    const signed char* __restrict__ A, const signed char* __restrict__ W,
    const float* __restrict__ inv_sa, const float* __restrict__ wsc, int widx,
    const float* __restrict__ bias, float* __restrict__ out)
{
  __shared__ __align__(16) signed char lds[131072];
  constexpr int NT = K / 128;
  const int tid = threadIdx.x;
  const int wv = tid >> 6, ln = tid & 63;
  const int wr = wv >> 2, wc = wv & 3;          // 2 x 4 wave grid
  const int g = ln >> 4, rl = ln & 15;
  const int colswz = (rl & 7) << 4;             // read-side 3-bit XOR

  // XCD-aware block swizzle (nwg % 8 == 0 for all our grids)
  const int nwg = gridDim.x * gridDim.y;
  int lbid = blockIdx.y * gridDim.x + blockIdx.x;
  lbid = (lbid & 7) * (nwg >> 3) + (lbid >> 3);
  const int bn = lbid % gridDim.x, bm = lbid / gridDim.x;

  const signed char* Abase = A + (size_t)bm * 256 * K;
  const signed char* Wbase = W + (size_t)bn * 256 * K;

  // staging: LDS chunk c (linear dest) sources global chunk c ^ ((c>>3)&7).
  const int c0 = tid, c1 = 512 + tid;
  const int r0 = c0 >> 3, k0c = ((c0 ^ (c0 >> 3)) & 7) * 16;
  const int r1 = c1 >> 3, k1c = ((c1 ^ (c1 >> 3)) & 7) * 16;

  auto stage = [&](int tt) {               // full tile: A 32KB + B 32KB, 8 GLDS
    if (tt >= NT) return;
    signed char* dA = lds + ((tt & 1) << 16);
    signed char* dB = dA + 32768;
    const signed char* gA = Abase + (size_t)tt * 128;
    const signed char* gB = Wbase + (size_t)tt * 128;
    GLDS16(gA + (size_t)r0 * K + k0c,         dA + (c0 << 4));
    GLDS16(gA + (size_t)r1 * K + k1c,         dA + (c1 << 4));
    GLDS16(gA + (size_t)(128 + r0) * K + k0c, dA + 16384 + (c0 << 4));
    GLDS16(gA + (size_t)(128 + r1) * K + k1c, dA + 16384 + (c1 << 4));
    GLDS16(gB + (size_t)r0 * K + k0c,         dB + (c0 << 4));
    GLDS16(gB + (size_t)r1 * K + k1c,         dB + (c1 << 4));
    GLDS16(gB + (size_t)(128 + r0) * K + k0c, dB + 16384 + (c0 << 4));
    GLDS16(gB + (size_t)(128 + r1) * K + k1c, dB + 16384 + (c1 << 4));
  };

  i32x4_t acc[8][4];
  #pragma unroll
  for (int m = 0; m < 8; ++m)
    #pragma unroll
    for (int n = 0; n < 4; ++n) acc[m][n] = (i32x4_t){0, 0, 0, 0};

  const int myAoff = wr * 16384;
  const int myBoff = 32768 + (wc >> 1) * 16384 + (wc & 1) * 8192;

  // prologue
  stage(0); stage(1);
  asm volatile("s_waitcnt vmcnt(8)" ::: "memory");
  __builtin_amdgcn_s_barrier();

  for (int t = 0; t < NT; ++t) {
    const signed char* base = lds + ((t & 1) << 16);
    const signed char* mA = base + myAoff;
    const signed char* mB = base + myBoff;

    i32x4_t bfr[4][2], afr[8][2];
    #pragma unroll
    for (int n = 0; n < 4; ++n)
      #pragma unroll
      for (int ks = 0; ks < 2; ++ks)
        bfr[n][ks] = *(const i32x4_t*)(mB + (n * 16 + rl) * 128
                                       + ((ks * 64 + g * 16) ^ colswz));
    #pragma unroll
    for (int m = 0; m < 8; ++m)
      #pragma unroll
      for (int ks = 0; ks < 2; ++ks)
        afr[m][ks] = *(const i32x4_t*)(mA + (m * 16 + rl) * 128
                                       + ((ks * 64 + g * 16) ^ colswz));

    __builtin_amdgcn_s_setprio(1);
    #pragma unroll
    for (int m = 0; m < 8; ++m)
      #pragma unroll
      for (int n = 0; n < 4; ++n)
        #pragma unroll
        for (int ks = 0; ks < 2; ++ks)
          acc[m][n] = __builtin_amdgcn_mfma_i32_16x16x64_i8(
              afr[m][ks], bfr[n][ks], acc[m][n], 0, 0, 0);
    __builtin_amdgcn_s_setprio(0);

    asm volatile("s_waitcnt lgkmcnt(0)" ::: "memory");
    __builtin_amdgcn_s_barrier();            // all waves done reading buf[cur]
    stage(t + 2);                            // refill buf[cur] with tile t+2
    if (t + 2 < NT) asm volatile("s_waitcnt vmcnt(8)" ::: "memory");
    else            asm volatile("s_waitcnt vmcnt(0)" ::: "memory");
    __builtin_amdgcn_s_barrier();            // tile t+1 confirmed resident
  }

  // -------- epilogue --------
  const float invw = wsc[widx * 2 + 1];
  const int row0 = bm * 256 + wr * 128;
  const int col0 = bn * 256 + wc * 64;
  #pragma unroll
  for (int m = 0; m < 8; ++m) {
    #pragma unroll
    for (int r = 0; r < 4; ++r) {
      const int gb = row0 + m * 16 + g * 4 + r;
      const float fa = inv_sa[gb] * invw;
      #pragma unroll
      for (int n = 0; n < 4; ++n) {
        const int go = col0 + n * 16 + rl;
        const float v = (float)acc[m][n][r] * fa + bias[go];
        out[(size_t)gb * N + go] = TANH ? tanhf(v) : v;
      }
    }
  }
}

// ---------------- driver ----------------------------------------------------
extern "C" void kernel_launch(void* const* d_in, const int* in_sizes, int n_in,
                              void* d_out, int out_size, void* d_ws, size_t ws_size,
                              hipStream_t stream)
{
  const float* x  = (const float*)d_in[0];
  const float* w1 = (const float*)d_in[1]; const float* b1 = (const float*)d_in[2];
  const float* w2 = (const float*)d_in[3]; const float* b2 = (const float*)d_in[4];
  const float* w3 = (const float*)d_in[5]; const float* b3 = (const float*)d_in[6];
  const float* w4 = (const float*)d_in[7]; const float* b4 = (const float*)d_in[8];
  float* out = (float*)d_out;

  constexpr int B = 8192, DIN = 1024, H = 4096, DOUT = 1024;
  char* ws = (char*)d_ws;
  size_t off = 0;
  float*       hbuf = (float*)(ws + off);        off += (size_t)B * H * 4;
  signed char* xq   = (signed char*)(ws + off);  off += (size_t)B * H;
  signed char* wq   = (signed char*)(ws + off);  off += (size_t)H * H;
  float*       inv_sa = (float*)(ws + off);      off += (size_t)B * 4;
  double*      part = (double*)(ws + off);       off += 1024 * 8;
  float*       wsc  = (float*)(ws + off);        off += 64;

  absmean_part_k<<<1024, 256, 0, stream>>>(w1, H * DIN / 4, part);
  absmean_fin_k<<<1, 256, 0, stream>>>(part, 1024, (double)H * DIN, wsc, 0);
  absmean_part_k<<<1024, 256, 0, stream>>>(w2, H * H / 4, part);
  absmean_fin_k<<<1, 256, 0, stream>>>(part, 1024, (double)H * H, wsc, 1);
  absmean_part_k<<<1024, 256, 0, stream>>>(w3, H * H / 4, part);
  absmean_fin_k<<<1, 256, 0, stream>>>(part, 1024, (double)H * H, wsc, 2);
  absmean_part_k<<<1024, 256, 0, stream>>>(w4, DOUT * H / 4, part);
  absmean_fin_k<<<1, 256, 0, stream>>>(part, 1024, (double)DOUT * H, wsc, 3);

  // layer 1 (K=1024): 128^2 kernel
  act_quant_k<DIN><<<B, 256, 0, stream>>>(x, (unsigned int*)xq, inv_sa);
  quant_w_k<<<2048, 256, 0, stream>>>(w1, (unsigned int*)wq, wsc, 0, H * DIN / 4);
  gemm_bt<DIN, H, true><<<dim3(H / 128, B / 128), 256, 0, stream>>>(
      xq, wq, inv_sa, wsc, 0, b1, hbuf);

  // layer 2 (4096^2 x 8192): 256^2 minimal-sync dbuf
  act_quant_k<H><<<B, 256, 0, stream>>>(hbuf, (unsigned int*)xq, inv_sa);
  quant_w_k<<<2048, 256, 0, stream>>>(w2, (unsigned int*)wq, wsc, 1, H * H / 4);
  gemm2p<H, H, true><<<dim3(H / 256, B / 256), 512, 0, stream>>>(
      xq, wq, inv_sa, wsc, 1, b2, hbuf);

  // layer 3
  act_quant_k<H><<<B, 256, 0, stream>>>(hbuf, (unsigned int*)xq, inv_sa);
  quant_w_k<<<2048, 256, 0, stream>>>(w3, (unsigned int*)wq, wsc, 2, H * H / 4);
  gemm2p<H, H, true><<<dim3(H / 256, B / 256), 512, 0, stream>>>(
      xq, wq, inv_sa, wsc, 2, b3, hbuf);

  // layer 4 (N=1024): 128^2 kernel
  act_quant_k<H><<<B, 256, 0, stream>>>(hbuf, (unsigned int*)xq, inv_sa);
  quant_w_k<<<2048, 256, 0, stream>>>(w4, (unsigned int*)wq, wsc, 3, DOUT * H / 4);
  gemm_bt<H, DOUT, false><<<dim3(DOUT / 128, B / 128), 256, 0, stream>>>(
      xq, wq, inv_sa, wsc, 3, b4, out);
}